// Round 6
// baseline (257.395 us; speedup 1.0000x reference)
//
#include <hip/hip_runtime.h>
#include <math.h>

#define TOK 16384
#define DD  2048
#define EE  64
#define MT  64           // tokens per block -> grid 256
#define BK  32           // k per chunk
#define NKC 64           // chunks

typedef _Float16 half8  __attribute__((ext_vector_type(8)));
typedef float    floatx4 __attribute__((ext_vector_type(4)));

// async 16B global->LDS: gptr per-lane, lds ptr wave-uniform (HW adds lane*16)
#define GLD16(g, l) __builtin_amdgcn_global_load_lds(                          \
    (__attribute__((address_space(1))) const void*)(g),                        \
    (__attribute__((address_space(3))) void*)(l), 16, 0, 0)

// ---- W pre-split: f32 -> (hi,lo) f16, frag-major layout ----
// wf frag index ((ct*64+kc)*2+s)*64+lane, 8 halves each.
// ct 0..3 = gate col-tiles (cols (ct&3)*16+cl), ct 4..7 = noise col-tiles.
__global__ void build_wf(const float* __restrict__ Wg, const float* __restrict__ Wn,
                         _Float16* __restrict__ wf) {
  int tid  = blockIdx.x * 256 + threadIdx.x;   // 32768 threads
  int lane = tid & 63;
  int kc   = (tid >> 6) & 63;
  int ct   = tid >> 12;                        // 0..7
  int col  = (ct & 3) * 16 + (lane & 15);
  int k    = kc * 32 + (lane >> 4) * 8;
  const float* W = (ct < 4) ? Wg : Wn;
  const float* src = W + (size_t)col * DD + k;
  float4 a = *reinterpret_cast<const float4*>(src);
  float4 b = *reinterpret_cast<const float4*>(src + 4);
  float v[8] = {a.x, a.y, a.z, a.w, b.x, b.y, b.z, b.w};
  half8 hi, lo;
#pragma unroll
  for (int j = 0; j < 8; ++j) {
    _Float16 h = (_Float16)v[j];
    hi[j] = h;
    lo[j] = (_Float16)(v[j] - (float)h);
  }
  size_t base = (((size_t)(ct * 64 + kc) * 2 + 0) * 64 + lane) * 8;
  *reinterpret_cast<half8*>(wf + base)       = hi;
  *reinterpret_cast<half8*>(wf + base + 512) = lo;
}

// Block 512 thr = 8 waves. wave w: cg=w&3 -> expert cols [cg*16,+16) (gate AND
// noise, lane-paired); mh=w>>2 -> token half. Double-buffered LDS staged with
// global_load_lds (no dest VGPRs -> loads stay in flight across compute).
// LDS: buf[p] @ p*24576: xTile 8192 (64 tok x 32 k f32, k-granules XOR-swizzled
// by row&7) | bFrags 16384 (16 pieces x 1KB, piece=ct*2+s).
// Epilogue union: Vb[64][66] @0 | Eb @16896 | isum @33792 | ti @34048 | tp @34560
__global__ __launch_bounds__(512, 2)
void gating_kernel(const float* __restrict__ x, const float* __restrict__ rn,
                   const _Float16* __restrict__ wf, const float* __restrict__ bg,
                   float* __restrict__ out,
                   float* __restrict__ cnt_g, float* __restrict__ psum_g) {
  __shared__ char smem[49152];
  float* Vb   = (float*)smem;                  // stride 66
  float* Eb   = (float*)(smem + 16896);        // stride 66
  float* isum = (float*)(smem + 33792);
  int*   ti   = (int*)(smem + 34048);
  float* tp   = (float*)(smem + 34560);

  const int t  = threadIdx.x;
  const int w  = t >> 6;
  const int l  = t & 63;
  const int q  = l >> 4;
  const int cl = l & 15;
  const int cg = w & 3;        // expert col group
  const int mh = w >> 2;       // token half
  const int c  = cg * 16 + cl;
  const int t0 = blockIdx.x * MT;

  // staging roles: wave w stages tokens [w*8,+8); lane: u=l>>3 token, sv=l&7
  // fetches k-granule (sv ^ u) so LDS position p holds global granule p ^ u.
  const int su = l >> 3;
  const int sv = l & 7;
  const float* xg = x + (size_t)(t0 + w * 8 + su) * DD + ((sv ^ su) * 4);
  const _Float16* bsrc0 = wf + (size_t)l * 8;   // + ((w*64+kc)*2)*512 per chunk

#define STAGE(kc_, p_)                                                         \
  {                                                                            \
    char* bX = smem + (p_) * 24576;                                            \
    GLD16(xg + (kc_) * BK, bX + w * 1024);                                     \
    const _Float16* bs = bsrc0 + ((size_t)(w * 64 + (kc_)) * 2) * 512;         \
    GLD16(bs,       bX + 8192 + (2 * w) * 1024);                               \
    GLD16(bs + 512, bX + 8192 + (2 * w + 1) * 1024);                           \
  }

  // epilogue operands preloaded (held across loop; hides their latency)
  const float bgv = bg[c];
  float rnv[2][4];
#pragma unroll
  for (int i = 0; i < 2; ++i)
#pragma unroll
    for (int r = 0; r < 4; ++r)
      rnv[i][r] = rn[(size_t)(t0 + (mh * 2 + i) * 16 + q * 4 + r) * EE + c];

  floatx4 accg[2], accn[2];
#pragma unroll
  for (int i = 0; i < 2; ++i) { accg[i] = (floatx4)0.f; accn[i] = (floatx4)0.f; }

  STAGE(0, 0)

  for (int kc = 0; kc < NKC; ++kc) {
    const int p = kc & 1;
    char* bufX = smem + p * 24576;
    char* bufB = bufX + 8192;
    __syncthreads();                 // buf[p] staged (vmcnt drained at barrier)
    if (kc + 1 < NKC) STAGE(kc + 1, p ^ 1)   // async: in flight across compute

    half8 Bg[2], Bn[2];
#pragma unroll
    for (int s = 0; s < 2; ++s) {
      Bg[s] = *reinterpret_cast<const half8*>(bufB + (cg * 2 + s) * 1024 + l * 16);
      Bn[s] = *reinterpret_cast<const half8*>(bufB + ((4 + cg) * 2 + s) * 1024 + l * 16);
    }
#pragma unroll
    for (int i = 0; i < 2; ++i) {
      const int row = (mh * 2 + i) * 16 + cl;
      const int r7  = row & 7;
      const float4 g0 = *reinterpret_cast<const float4*>(
          bufX + row * 128 + (((2 * q) ^ r7) << 4));
      const float4 g1 = *reinterpret_cast<const float4*>(
          bufX + row * 128 + (((2 * q + 1) ^ r7) << 4));
      float vv[8] = {g0.x, g0.y, g0.z, g0.w, g1.x, g1.y, g1.z, g1.w};
      half8 Ah, Al;
#pragma unroll
      for (int j = 0; j < 8; ++j) {
        _Float16 h = (_Float16)vv[j];
        Ah[j] = h;
        Al[j] = (_Float16)(vv[j] - (float)h);
      }
      accg[i] = __builtin_amdgcn_mfma_f32_16x16x32_f16(Ah, Bg[0], accg[i], 0, 0, 0);
      accn[i] = __builtin_amdgcn_mfma_f32_16x16x32_f16(Ah, Bn[0], accn[i], 0, 0, 0);
      accg[i] = __builtin_amdgcn_mfma_f32_16x16x32_f16(Ah, Bg[1], accg[i], 0, 0, 0);
      accn[i] = __builtin_amdgcn_mfma_f32_16x16x32_f16(Ah, Bn[1], accn[i], 0, 0, 0);
      accg[i] = __builtin_amdgcn_mfma_f32_16x16x32_f16(Al, Bg[0], accg[i], 0, 0, 0);
      accn[i] = __builtin_amdgcn_mfma_f32_16x16x32_f16(Al, Bn[0], accn[i], 0, 0, 0);
    }
  }
#undef STAGE

  __syncthreads();   // all buf reads done; smem becomes Vb/Eb

  // noisy logit + exp, in-register (gate/noise lane-paired); each (tok,col) once
#pragma unroll
  for (int i = 0; i < 2; ++i)
#pragma unroll
    for (int r = 0; r < 4; ++r) {
      const int tk = (mh * 2 + i) * 16 + q * 4 + r;   // C/D: row = q*4+r
      float g  = accg[i][r] + bgv;
      float h  = accn[i][r];
      float sp = (h > 20.f) ? h : log1pf(expf(h));
      float v  = g + rnv[i][r] * (sp + 0.01f);
      Vb[tk * 66 + c] = v;
      Eb[tk * 66 + c] = expf(v);
    }
  __syncthreads();

  // per-token top-2 + softmax denom (64 threads)
  if (t < MT) {
    float v1 = -1e30f, v2 = -1e30f;
    int   i1 = 0, i2 = 0;
    float s = 0.f;
    for (int e = 0; e < EE; ++e) {
      float v = Vb[t * 66 + e];
      s += Eb[t * 66 + e];
      if (v > v1)      { v2 = v1; i2 = i1; v1 = v; i1 = e; }
      else if (v > v2) { v2 = v;  i2 = e; }
    }
    isum[t] = 1.f / s;
    ti[t * 2 + 0] = i1; ti[t * 2 + 1] = i2;
    float e2 = expf(v2 - v1);
    float dn = 1.f + e2;
    tp[t * 2 + 0] = 1.f / dn;
    tp[t * 2 + 1] = e2 / dn;
  }
  __syncthreads();

  // sparse out: patched zero-fill, coalesced (8 floats/thread, 512 thr)
  {
    const int m  = t >> 3;
    const int c0 = (t & 7) * 8;
    const int i1 = ti[m * 2 + 0], i2 = ti[m * 2 + 1];
    const float p1 = tp[m * 2 + 0], p2 = tp[m * 2 + 1];
    float o[8];
#pragma unroll
    for (int j = 0; j < 8; ++j) {
      const int col = c0 + j;
      o[j] = (col == i1) ? p1 : ((col == i2) ? p2 : 0.f);
    }
    float* dst = out + (size_t)(t0 + m) * EE + c0;
    *reinterpret_cast<float4*>(dst)     = make_float4(o[0], o[1], o[2], o[3]);
    *reinterpret_cast<float4*>(dst + 4) = make_float4(o[4], o[5], o[6], o[7]);
  }

  // aux partials: per-expert psum & count
  if (t < EE) {
    float s = 0.f;
    int   cn = 0;
#pragma unroll
    for (int m = 0; m < MT; ++m) {
      s  += Eb[m * 66 + t] * isum[m];
      cn += (ti[m * 2 + 0] == t) + (ti[m * 2 + 1] == t);
    }
    atomicAdd(&psum_g[t], s);
    atomicAdd(&cnt_g[t], (float)cn);
  }
}

__global__ void aux_kernel(const float* __restrict__ cnt_g,
                           const float* __restrict__ psum_g,
                           float* __restrict__ out) {
  int e = threadIdx.x;  // 64 lanes, one wave
  float v = cnt_g[e] * psum_g[e];
#pragma unroll
  for (int o = 32; o > 0; o >>= 1) v += __shfl_down(v, o);
  if (e == 0)
    out[(size_t)TOK * EE] = v * ((float)EE / ((float)TOK * (float)TOK));
}

extern "C" void kernel_launch(void* const* d_in, const int* in_sizes, int n_in,
                              void* d_out, int out_size, void* d_ws, size_t ws_size,
                              hipStream_t stream) {
  const float* x  = (const float*)d_in[0];
  const float* rn = (const float*)d_in[1];
  const float* Wg = (const float*)d_in[2];
  const float* bg = (const float*)d_in[3];
  const float* Wn = (const float*)d_in[4];
  float* out    = (float*)d_out;
  float* cnt_g  = (float*)d_ws;
  float* psum_g = cnt_g + EE;
  _Float16* wf  = (_Float16*)((float*)d_ws + 128);   // 1 MiB of pre-split W frags

  hipMemsetAsync(d_ws, 0, 2 * EE * sizeof(float), stream);
  build_wf<<<128, 256, 0, stream>>>(Wg, Wn, wf);
  gating_kernel<<<TOK / MT, 512, 0, stream>>>(x, rn, wf, bg, out, cnt_g, psum_g);
  aux_kernel<<<1, 64, 0, stream>>>(cnt_g, psum_g, out);
}